// Round 21
// baseline (458.483 us; speedup 1.0000x reference)
//
#include <hip/hip_runtime.h>
#include <hip/hip_bf16.h>

#define B_    16
#define C_    96
#define H_    224
#define W_    224
#define COUT_ 96
#define GH_   14
#define GW_   14
#define P_    196          // GH_*GW_
#define HW_   (H_*W_)      // 50176
#define NCH_  12           // 8-channel chunks
#define APITCH 325         // A plane pitch in px (5200 B; mod-128 spread)

#define AS1 __attribute__((address_space(1)))
#define AS3 __attribute__((address_space(3)))

typedef __attribute__((ext_vector_type(8)))  unsigned short ushort8;
typedef __attribute__((ext_vector_type(8)))  short          short8;   // MFMA bf16x8 operand
typedef __attribute__((ext_vector_type(4)))  float          f32x4;
typedef __attribute__((ext_vector_type(16))) float          f32x16;   // 32x32 accumulator

__device__ __forceinline__ unsigned short f2bf(float f) {
    union { __hip_bfloat16 h; unsigned short u; } cv;
    cv.h = __float2bfloat16(f);
    return cv.u;
}

// ---------------------------------------------------------------------------
// Kernel 1 (merged): blocks [0,3136) = depthwise 3x3 -> sa (R5-proven);
// tail blocks = repack of -> ofb4 (32x32 fragment order) + zero-page.
//   ofb4[tap][q][nt][lane][8]: cout = nt*32 + (l&31), c = q*16 + (l>>5)*8 + j.
// ---------------------------------------------------------------------------
__global__ __launch_bounds__(256) void sa_prep_kernel(const float* __restrict__ x,
                                                      const float* __restrict__ pf,
                                                      unsigned short* __restrict__ sa,
                                                      const float* __restrict__ of,
                                                      unsigned short* __restrict__ ofb4,
                                                      unsigned short* __restrict__ zp) {
    int bid = blockIdx.x;

    if (bid >= B_ * P_) {                  // ---- prep tail ----
        int pb = bid - B_ * P_;
        if (pb == 0 && threadIdx.x < 128) zp[threadIdx.x] = 0;
        int e = pb * 256 + threadIdx.x;    // 9*6*3*64*8 = 82944
        if (e < 82944) {
            int j   = e & 7;
            int l   = (e >> 3) & 63;
            int nt  = (e >> 9) % 3;
            int q   = (e / 1536) % 6;
            int tap = e / 9216;
            int cout = nt * 32 + (l & 31);
            int c    = q * 16 + (l >> 5) * 8 + j;
            ofb4[e] = f2bf(of[((size_t)cout * 96 + c) * 9 + tap]);
        }
        return;
    }

    int patch = bid % P_;
    int b     = bid / P_;
    int gh = patch / GW_, gw = patch % GW_;
    int t  = threadIdx.x;
    int py = t >> 4, px = t & 15;
    int y  = gh * 16 + py, xx = gw * 16 + px;

    __shared__ float xs[2][8][256];    // 16 KB double-buffered x slice

    const float* xp0 = x + (size_t)b * C_ * HW_ + (size_t)y * W_ + xx;

    float lf[8];
    #pragma unroll
    for (int ch = 0; ch < 8; ++ch) lf[ch] = xp0[(size_t)ch * HW_];

    for (int cc = 0; cc < NCH_; ++cc) {
        int buf = cc & 1;
        #pragma unroll
        for (int ch = 0; ch < 8; ++ch) xs[buf][ch][t] = lf[ch];
        __syncthreads();
        if (cc < NCH_ - 1) {
            #pragma unroll
            for (int ch = 0; ch < 8; ++ch)
                lf[ch] = xp0[(size_t)((cc + 1) * 8 + ch) * HW_];
        }

        ushort8 v;
        #pragma unroll
        for (int ch = 0; ch < 8; ++ch) {
            const float* wgt = pf + ((size_t)(cc * 8 + ch) * P_ + patch) * 9;
            float a = 0.f;
            #pragma unroll
            for (int dy = -1; dy <= 1; ++dy) {
                int yy = py + dy;
                if ((unsigned)yy < 16u) {
                    #pragma unroll
                    for (int dx = -1; dx <= 1; ++dx) {
                        int xq = px + dx;
                        if ((unsigned)xq < 16u)
                            a = fmaf(xs[buf][ch][yy * 16 + xq],
                                     wgt[(dy + 1) * 3 + (dx + 1)], a);
                    }
                }
            }
            v[ch] = f2bf(a);
        }
        *(ushort8*)&sa[(((size_t)(b * NCH_ + cc) * H_ + y) * W_ + xx) * 8] = v;
    }
}

// ---------------------------------------------------------------------------
// Kernel 2: implicit-GEMM conv via mfma_f32_32x32x16_bf16 + exact GELU.
// R21: same FLOP in HALF the MFMA instructions (2x pipe occupancy each,
// +15% ubench ceiling 2382 vs 2075 TF), half the per-FLOP load count
// (each bf feeds 2 M-tiles). Full-patch block, 4 waves; wave = 2 M-tiles
// (64 px) x 3 N-tiles (96 couts) = acc[2][3] f32x16 (96 regs, (256,2)).
//   A frag: row m = l&31 -> px = w*64 + mt*32 + m; k = (l>>5)*8+j ->
//           plane = 4cs + 2qi + (l>>5), contiguous ushort8 in plane-major.
//   B frag: ofb4 fragment-order, base + lane*16B coalesced.
//   C/D:    col(cout-part) = l&31, row m = (r&3)+8*(r>>2)+4*(l>>5)
//           [m74/m101-verified]. Scalar stores; same-wave regs cover all 16
//           x of each 64B line -> L2 merges, WRITE stays ~301 MB.
// Pipeline: R17's depth-1 fence (bf+af issued for T+1, sched_barrier(0)).
// ---------------------------------------------------------------------------
__global__ __launch_bounds__(256, 2) void conv2_mfma(const unsigned short* __restrict__ sa,
                                                     const unsigned short* __restrict__ ofb4,
                                                     const unsigned short* __restrict__ zp,
                                                     float* __restrict__ out) {
    // XCD-aware swizzle (3136 % 8 == 0 -> bijective)
    int bid0 = blockIdx.x;
    int bid  = (bid0 % 8) * (3136 / 8) + bid0 / 8;
    int patch = bid % P_;
    int b     = bid / P_;
    int gh = patch / GW_, gw = patch % GW_;
    int y0 = gh * 16, x0 = gw * 16;

    int t = threadIdx.x;
    int w = t >> 6, l = t & 63;             // wave w owns px 64w..64w+63
    int hi = l >> 5;

    __shared__ ushort8 at8[4096];           // 12 planes x 325 pitch = 3900 (+196 trash) = 65536 B

    // ---- single staging burst: 18x18 halo, plane-major, 325-px pitch ----
    #pragma unroll
    for (int i = 0; i < 16; ++i) {
        int v = t + i * 256;                // 0..4095; real: v<3900 && hpx<324
        const unsigned short* src = zp;
        if (v < 3900) {
            int ccl = v / APITCH, hpx = v - ccl * APITCH;
            if (hpx < 324) {
                int gy = y0 - 1 + hpx / 18, gx = x0 - 1 + hpx % 18;
                if ((unsigned)gy < (unsigned)H_ && (unsigned)gx < (unsigned)W_)
                    src = &sa[(((size_t)(b * NCH_ + ccl) * H_ + gy) * W_ + gx) * 8];
            }
        }
        __builtin_amdgcn_global_load_lds((const AS1 unsigned int*)src,
                                         (AS3 unsigned int*)&at8[v], 16, 0, 0);
    }

    f32x16 acc[2][3];
    #pragma unroll
    for (int mt = 0; mt < 2; ++mt)
        #pragma unroll
        for (int nt = 0; nt < 3; ++nt)
            acc[mt][nt] = (f32x16)0.f;

    __syncthreads();                        // drain DMA; tile visible; queue EMPTY

    const unsigned short* at = (const unsigned short*)at8;  // [plane][325 px][8ch]

    // step T = tap*3 + cs (cs = 32-ch group = q pair {2cs, 2cs+1})
    short8 bfA[6], bfB[6], afA[4], afB[4];
    auto LOADBF = [&](short8* dst, int T) {
        const unsigned short* p = ofb4 + (size_t)(T / 3) * 9216 + (T % 3) * 3072 + l * 8;
        #pragma unroll
        for (int d = 0; d < 6; ++d)         // d = qi*3 + nt
            dst[d] = *(const short8*)&p[d * 512];
    };
    auto LOADAF = [&](short8* dst, int T) {
        int tap = T / 3, cs = T % 3;
        int ky = tap / 3, kx = tap % 3;
        int hx = (l & 15) + kx;
        int yb = 4 * w + ((l >> 4) & 1);    // y' base for m = l&31
        #pragma unroll
        for (int mt = 0; mt < 2; ++mt)
            #pragma unroll
            for (int qi = 0; qi < 2; ++qi) {
                int plane = 4 * cs + 2 * qi + hi;
                int hy = yb + 2 * mt + ky;
                dst[mt * 2 + qi] = *(const short8*)&at[(plane * APITCH + hy * 18 + hx) * 8];
            }
    };

    LOADBF(bfA, 0);
    LOADAF(afA, 0);
    #pragma unroll                          // full unroll: ring naming static
    for (int T = 0; T < 27; ++T) {
        short8* bcur = (T & 1) ? bfB : bfA;
        short8* bnxt = (T & 1) ? bfA : bfB;
        short8* acur = (T & 1) ? afB : afA;
        short8* anxt = (T & 1) ? afA : afB;
        if (T + 1 < 27) {
            LOADBF(bnxt, T + 1);            // issue-early (T14)
            LOADAF(anxt, T + 1);
        }
        __builtin_amdgcn_sched_barrier(0);  // pin T+1 issues above the burst

        #pragma unroll
        for (int mt = 0; mt < 2; ++mt)
            #pragma unroll
            for (int nt = 0; nt < 3; ++nt)
                #pragma unroll
                for (int qi = 0; qi < 2; ++qi)
                    acc[mt][nt] = __builtin_amdgcn_mfma_f32_32x32x16_bf16(
                        acur[mt * 2 + qi], bcur[qi * 3 + nt], acc[mt][nt], 0, 0, 0);
    }

    // ---- epilogue: exact GELU + scalar stores (L2 merges within wave) ----
    #pragma unroll
    for (int mt = 0; mt < 2; ++mt) {
        #pragma unroll
        for (int nt = 0; nt < 3; ++nt) {
            int cout = nt * 32 + (l & 31);
            float* ob = out + ((size_t)b * COUT_ + cout) * HW_;
            #pragma unroll
            for (int r = 0; r < 16; ++r) {
                int m  = (r & 3) + 8 * (r >> 2) + 4 * hi;
                int px = w * 64 + mt * 32 + m;
                int gy = y0 + (px >> 4), gx = x0 + (px & 15);
                float vv = acc[mt][nt][r];
                ob[(size_t)gy * W_ + gx] = 0.5f * vv * (1.0f + erff(vv * 0.70710678118f));
            }
        }
    }
}

extern "C" void kernel_launch(void* const* d_in, const int* in_sizes, int n_in,
                              void* d_out, int out_size, void* d_ws, size_t ws_size,
                              hipStream_t stream) {
    const float* x  = (const float*)d_in[0];
    const float* pf = (const float*)d_in[1];
    const float* of = (const float*)d_in[2];
    float* out = (float*)d_out;

    unsigned short* sa   = (unsigned short*)d_ws;                       // 154,140,672 B
    unsigned short* ofb4 = (unsigned short*)((char*)d_ws + 154140672);  // + 165,888 B
    unsigned short* zp   = (unsigned short*)((char*)d_ws + 154306560);  // + 256 B zero-page

    sa_prep_kernel<<<B_ * P_ + 324, 256, 0, stream>>>(x, pf, sa, of, ofb4, zp);
    conv2_mfma<<<B_ * P_, 256, 0, stream>>>(sa, ofb4, zp, out);
}

// Round 22
// 360.672 us; speedup vs baseline: 1.2712x; 1.2712x over previous
//
#include <hip/hip_runtime.h>
#include <hip/hip_bf16.h>

#define B_    16
#define C_    96
#define H_    224
#define W_    224
#define COUT_ 96
#define GH_   14
#define GW_   14
#define P_    196          // GH_*GW_
#define HW_   (H_*W_)      // 50176
#define NCH_  12           // 8-channel chunks
#define APITCH 181         // A-tile plane pitch in px

#define AS1 __attribute__((address_space(1)))
#define AS3 __attribute__((address_space(3)))

typedef __attribute__((ext_vector_type(8))) unsigned short ushort8;
typedef __attribute__((ext_vector_type(8))) short        short8;   // MFMA bf16x8 operand
typedef __attribute__((ext_vector_type(4))) float        f32x4;

__device__ __forceinline__ unsigned short f2bf(float f) {
    union { __hip_bfloat16 h; unsigned short u; } cv;
    cv.h = __float2bfloat16(f);
    return cv.u;
}

// ---------------------------------------------------------------------------
// Kernel 1 (merged): blocks [0, 3136) = per-patch depthwise 3x3 -> sa;
// blocks [3136, 3460) = filter repack -> ofb3 (fragment order) + zero-page.
// R22: x-staging VECTORIZED (float4, 16 B/lane, 2 loads/thread/chunk vs 8
// scalar) -- the last scalar-load hot loop (G13). Compute path unchanged.
// ---------------------------------------------------------------------------
__global__ __launch_bounds__(256) void sa_prep_kernel(const float* __restrict__ x,
                                                      const float* __restrict__ pf,
                                                      unsigned short* __restrict__ sa,
                                                      const float* __restrict__ of,
                                                      unsigned short* __restrict__ ofb3,
                                                      unsigned short* __restrict__ zp) {
    int bid = blockIdx.x;

    if (bid >= B_ * P_) {                  // ---- prep tail: ofb3 + zp ----
        int pb = bid - B_ * P_;
        if (pb == 0 && threadIdx.x < 128) zp[threadIdx.x] = 0;
        int e = pb * 256 + threadIdx.x;    // 9*3*6*64*8 = 82944
        if (e < 82944) {
            int j    = e & 7;
            int l    = (e >> 3) & 63;
            int ni   = (e >> 9) % 6;
            int cs   = (e / 3072) % 3;
            int tap  = e / 9216;
            int cout = ni * 16 + (l & 15);
            int c    = cs * 32 + (l >> 4) * 8 + j;
            ofb3[e] = f2bf(of[((size_t)cout * 96 + c) * 9 + tap]);
        }
        return;
    }

    // ---- sa part ----
    int patch = bid % P_;
    int b     = bid / P_;
    int gh = patch / GW_, gw = patch % GW_;
    int t  = threadIdx.x;
    int py = t >> 4, px = t & 15;
    int y  = gh * 16 + py, xx = gw * 16 + px;

    __shared__ f32x4 xs4[2][8][64];    // 16 KB double-buffered x slice (f32x4 view)

    // staging task for this thread: 2 float4 per chunk
    // idx = t + i*256 in [0,512): ch = idx>>6, r = idx&63 -> px row r>>2, col (r&3)*4
    const float* xbase = x + (size_t)(b * 96) * HW_ + (size_t)(gh * 16) * W_ + gw * 16;
    int ch0 = t >> 6, r0 = t & 63;
    int ch1 = (t + 256) >> 6, r1 = (t + 256) & 63;
    const float* g0 = xbase + (size_t)(r0 >> 2) * W_ + (r0 & 3) * 4;
    const float* g1 = xbase + (size_t)(r1 >> 2) * W_ + (r1 & 3) * 4;

    f32x4 lfA, lfB;
    lfA = *(const f32x4*)(g0 + (size_t)ch0 * HW_);
    lfB = *(const f32x4*)(g1 + (size_t)ch1 * HW_);

    for (int cc = 0; cc < NCH_; ++cc) {
        int buf = cc & 1;
        xs4[buf][ch0][r0] = lfA;
        xs4[buf][ch1][r1] = lfB;
        __syncthreads();
        if (cc < NCH_ - 1) {
            lfA = *(const f32x4*)(g0 + (size_t)((cc + 1) * 8 + ch0) * HW_);
            lfB = *(const f32x4*)(g1 + (size_t)((cc + 1) * 8 + ch1) * HW_);
        }

        const float* xsf = (const float*)&xs4[buf][0][0];   // [8][256] f32 view
        ushort8 v;
        #pragma unroll
        for (int ch = 0; ch < 8; ++ch) {
            const float* wgt = pf + ((size_t)(cc * 8 + ch) * P_ + patch) * 9;  // uniform -> s_load
            float a = 0.f;
            #pragma unroll
            for (int dy = -1; dy <= 1; ++dy) {
                int yy = py + dy;
                if ((unsigned)yy < 16u) {
                    #pragma unroll
                    for (int dx = -1; dx <= 1; ++dx) {
                        int xq = px + dx;
                        if ((unsigned)xq < 16u)
                            a = fmaf(xsf[ch * 256 + yy * 16 + xq],
                                     wgt[(dy + 1) * 3 + (dx + 1)], a);
                    }
                }
            }
            v[ch] = f2bf(a);
        }
        // lanes consecutive in x -> 16 B/lane fully coalesced
        *(ushort8*)&sa[(((size_t)(b * NCH_ + cc) * H_ + y) * W_ + xx) * 8] = v;
    }
}

// ---------------------------------------------------------------------------
// Kernel 2: implicit-GEMM MFMA conv + exact GELU, half-patch blocks.
// R20-proven best (conv2 ~230 us): half-patch, 3 blocks/CU, stage-once DMA,
// fragment-order bf (coalesced), af+bf depth-1 fence pipeline. Unchanged.
// ---------------------------------------------------------------------------
__global__ __launch_bounds__(256, 3) void conv2_mfma(const unsigned short* __restrict__ sa,
                                                     const unsigned short* __restrict__ ofb3,
                                                     const unsigned short* __restrict__ zp,
                                                     float* __restrict__ out) {
    // XCD-aware swizzle (6272 % 8 == 0 -> bijective); same-patch halves adjacent
    int bid0 = blockIdx.x;
    int bid  = (bid0 % 8) * (6272 / 8) + bid0 / 8;
    int half = bid & 1;
    int pid  = bid >> 1;
    int patch = pid % P_;
    int b     = pid / P_;
    int gh = patch / GW_, gw = patch % GW_;
    int y0 = gh * 16 + half * 8, x0 = gw * 16;   // 8x16 output region

    int t = threadIdx.x;
    int w = t >> 6, l = t & 63;
    int wm = w & 1, wn = w >> 1;            // 2 M-waves x 2 N-waves
    int mrow = l & 15, kgrp = l >> 4;

    __shared__ ushort8 at8[2304];           // 12 planes x 181 slots (+132 trash) = 36,864 B

    // ---- single staging burst: 10x18 halo, plane-major, 181-slot pitch ----
    #pragma unroll
    for (int i = 0; i < 9; ++i) {
        int v = t + i * 256;                // 0..2303; real: v<2172 && slot<180
        const unsigned short* src = zp;
        if (v < 2172) {
            int ccl = v / APITCH, hpx = v - ccl * APITCH;
            if (hpx < 180) {
                int gy = y0 - 1 + hpx / 18, gx = x0 - 1 + hpx % 18;
                if ((unsigned)gy < (unsigned)H_ && (unsigned)gx < (unsigned)W_)
                    src = &sa[(((size_t)(b * NCH_ + ccl) * H_ + gy) * W_ + gx) * 8];
            }
        }
        __builtin_amdgcn_global_load_lds((const AS1 unsigned int*)src,
                                         (AS3 unsigned int*)&at8[v], 16, 0, 0);
    }

    f32x4 acc[4][3];
    #pragma unroll
    for (int mi = 0; mi < 4; ++mi)
        #pragma unroll
        for (int ni = 0; ni < 3; ++ni)
            acc[mi][ni] = (f32x4)0.f;

    __syncthreads();                        // drain DMA; tile visible; queue EMPTY

    const unsigned short* at = (const unsigned short*)at8;  // [plane][181 px][8ch]

    // Pipelines: bf (global, fragment-order) and af (LDS) both 1 step ahead.
    short8 bfA[3], bfB[3], afA[4], afB[4];
    auto LOADBF = [&](short8* dst, int T) {
        const unsigned short* p = ofb3 + (size_t)(T / 3) * 9216 + (T % 3) * 3072
                                  + (wn * 3) * 512 + l * 8;
        #pragma unroll
        for (int nj = 0; nj < 3; ++nj)
            dst[nj] = *(const short8*)&p[nj * 512];
    };
    auto LOADAF = [&](short8* dst, int T) {
        int tap = T / 3, cs = T % 3;
        int ky = tap / 3, kx = tap % 3;
        #pragma unroll
        for (int mi = 0; mi < 4; ++mi)
            dst[mi] = *(const short8*)&at[((cs * 4 + kgrp) * APITCH
                                          + (wm * 4 + mi + ky) * 18
                                          + kx + mrow) * 8];
    };

    LOADBF(bfA, 0);
    LOADAF(afA, 0);
    #pragma unroll                          // full unroll: ring naming static (rule #20)
    for (int T = 0; T < 27; ++T) {
        short8* bcur = (T & 1) ? bfB : bfA;
        short8* bnxt = (T & 1) ? bfA : bfB;
        short8* acur = (T & 1) ? afB : afA;
        short8* anxt = (T & 1) ? afA : afB;
        if (T + 1 < 27) {
            LOADBF(bnxt, T + 1);            // global loads in flight (T14)
            LOADAF(anxt, T + 1);            // ds_reads in flight
        }
        __builtin_amdgcn_sched_barrier(0);  // pin all T+1 issues above the burst

        #pragma unroll
        for (int mi = 0; mi < 4; ++mi)
            #pragma unroll
            for (int nj = 0; nj < 3; ++nj)
                acc[mi][nj] = __builtin_amdgcn_mfma_f32_16x16x32_bf16(
                    acur[mi], bcur[nj], acc[mi][nj], 0, 0, 0);
    }

    // ---- epilogue: exact GELU + f32x4 stores ----
    #pragma unroll
    for (int mi = 0; mi < 4; ++mi) {
        int gy = y0 + wm * 4 + mi;
        #pragma unroll
        for (int nj = 0; nj < 3; ++nj) {
            int cout = (wn * 3 + nj) * 16 + mrow;
            f32x4 gv;
            #pragma unroll
            for (int j = 0; j < 4; ++j) {
                float vv = acc[mi][nj][j];
                gv[j] = 0.5f * vv * (1.0f + erff(vv * 0.70710678118f));
            }
            *(f32x4*)&out[((size_t)b * COUT_ + cout) * HW_ + (size_t)gy * W_ +
                          x0 + kgrp * 4] = gv;
        }
    }
}

extern "C" void kernel_launch(void* const* d_in, const int* in_sizes, int n_in,
                              void* d_out, int out_size, void* d_ws, size_t ws_size,
                              hipStream_t stream) {
    const float* x  = (const float*)d_in[0];
    const float* pf = (const float*)d_in[1];
    const float* of = (const float*)d_in[2];
    float* out = (float*)d_out;

    unsigned short* sa   = (unsigned short*)d_ws;                       // 154,140,672 B
    unsigned short* ofb3 = (unsigned short*)((char*)d_ws + 154140672);  // + 165,888 B
    unsigned short* zp   = (unsigned short*)((char*)d_ws + 154306560);  // + 256 B zero-page

    sa_prep_kernel<<<B_ * P_ + 324, 256, 0, stream>>>(x, pf, sa, of, ofb3, zp);
    conv2_mfma<<<B_ * P_ * 2, 256, 0, stream>>>(sa, ofb3, zp, out);
}